// Round 8
// baseline (21.386 us; speedup 1.0000x reference)
//
#include <hip/hip_runtime.h>

// GCNConv, full upper-tri graph + self loops, B=512, N=64, C=O=256.
// out[b,i,:] = relu( (1/sqrt(i+1)) * sum_{j<=i} (X[b]W)[j,:]/sqrt(j+1) + bias )
//
// R9: counted-vmcnt pipeline. W loads first; g0+g1 X loads issued at t0;
// both barriers are lgkm-only (inline asm) so g1's loads and g0's stores are
// never drained by a barrier. g1 convert+ds_write happens right after gemm-g0
// (only g1's 8 loads outstanding -> clean wait), overlapping g0's epilogue.

#define BATCH 512
#define NNODE 64
#define CIN   256
#define COUT  256

typedef __bf16 bf16x8 __attribute__((ext_vector_type(8)));
typedef float  f32x4  __attribute__((ext_vector_type(4)));

// barrier that waits only on LDS ops (no vmcnt drain)
#define LGKM_BARRIER() asm volatile("s_waitcnt lgkmcnt(0)\n\ts_barrier" ::: "memory")

__global__ __launch_bounds__(512, 1) void gcn_fused(
    const float* __restrict__ X,
    const float* __restrict__ W,             // f32, [CIN][COUT] row-major
    const float* __restrict__ bias,
    float* __restrict__ out)
{
    __shared__ uint4 Xs4[2][2048];           // [graph][32KB] swizzled bf16 X
    const int tid  = threadIdx.x;
    const int lane = tid & 63;
    const int w    = tid >> 6;               // wave 0..7: cols [w*32, w*32+32)
    const int g    = lane >> 4;
    const int c    = lane & 15;
    const int colbase = w * 32;
    const int xg   = blockIdx.x * 2;

    const float* xb0 = X + (size_t)xg * (NNODE * CIN);
    const float* xb1 = xb0 + NNODE * CIN;

    // ---- 1) W fragments FIRST (L2-resident after first touch) ----
    // B[k = kk*32+g*8+j][col = colbase+nt*16+c] = W[k*COUT + col]
    bf16x8 bfr[8][2];                        // 64 VGPR
    {
        const float* Wp = W + colbase + c;
#pragma unroll
        for (int kk = 0; kk < 8; ++kk)
#pragma unroll
            for (int nt = 0; nt < 2; ++nt) {
                bf16x8 t;
#pragma unroll
                for (int j = 0; j < 8; ++j)
                    t[j] = (__bf16)Wp[(size_t)(kk * 32 + g * 8 + j) * COUT + nt * 16];
                bfr[kk][nt] = t;
            }
    }
    float bias_c[2];
#pragma unroll
    for (int nt = 0; nt < 2; ++nt)
        bias_c[nt] = bias[colbase + nt * 16 + c];

    // ---- 2) issue g0 X loads, then 3) g1 X loads (all in flight at ~t0) ----
    f32x4 pf[8];
#pragma unroll
    for (int i = 0; i < 4; ++i) {
        int ch  = tid + i * 512;             // 2048 chunks of 8 floats
        const f32x4* p = reinterpret_cast<const f32x4*>(
            xb0 + (ch >> 5) * CIN + ((ch & 31) << 3));
        pf[2 * i]     = p[0];
        pf[2 * i + 1] = p[1];
    }
    f32x4 pg[8];
#pragma unroll
    for (int i = 0; i < 4; ++i) {
        int ch  = tid + i * 512;
        const f32x4* p = reinterpret_cast<const f32x4*>(
            xb1 + (ch >> 5) * CIN + ((ch & 31) << 3));
        pg[2 * i]     = p[0];
        pg[2 * i + 1] = p[1];
    }

    // ---- 4) convert g0 -> LDS buf0 (compiler waits vmcnt(8): g1 in flight) ----
#pragma unroll
    for (int i = 0; i < 4; ++i) {
        int ch  = tid + i * 512;
        int row = ch >> 5;
        int c8  = (ch & 31) << 3;
        f32x4 v0 = pf[2 * i], v1 = pf[2 * i + 1];
        bf16x8 h;
        h[0] = (__bf16)v0[0]; h[1] = (__bf16)v0[1];
        h[2] = (__bf16)v0[2]; h[3] = (__bf16)v0[3];
        h[4] = (__bf16)v1[0]; h[5] = (__bf16)v1[1];
        h[6] = (__bf16)v1[2]; h[7] = (__bf16)v1[3];
        int byte = (row << 9) + (c8 << 1);
        byte ^= (row & 7) << 4;
        *reinterpret_cast<uint4*>((unsigned char*)Xs4[0] + byte) =
            __builtin_bit_cast(uint4, h);
    }

    float dd[4][4];                          // 1/sqrt(row+1) table
#pragma unroll
    for (int mt = 0; mt < 4; ++mt)
#pragma unroll
        for (int r = 0; r < 4; ++r)
            dd[mt][r] = rsqrtf((float)(mt * 16 + g * 4 + r + 1));

    const int swz = (c & 7) << 4;

    auto gemm = [&](const unsigned char* Xs, f32x4 (&acc)[4][2]) {
#pragma unroll
        for (int kk = 0; kk < 8; ++kk) {
            bf16x8 a[4];
#pragma unroll
            for (int mt = 0; mt < 4; ++mt) {
                int byte = ((mt * 16 + c) << 9) + (kk << 6) + (g << 4);
                byte ^= swz;
                a[mt] = *reinterpret_cast<const bf16x8*>(Xs + byte);
            }
#pragma unroll
            for (int mt = 0; mt < 4; ++mt)
#pragma unroll
                for (int nt = 0; nt < 2; ++nt)
                    acc[mt][nt] = __builtin_amdgcn_mfma_f32_16x16x32_bf16(
                        a[mt], bfr[kk][nt], acc[mt][nt], 0, 0, 0);
        }
    };

    auto epilogue = [&](f32x4 (&acc)[4][2], float* ob) {
        // per-lane inclusive scan within each 4-row chunk
        float t_[4][2];
#pragma unroll
        for (int mt = 0; mt < 4; ++mt)
#pragma unroll
            for (int nt = 0; nt < 2; ++nt) {
                f32x4 v = acc[mt][nt];
                v[0] *= dd[mt][0]; v[1] *= dd[mt][1];
                v[2] *= dd[mt][2]; v[3] *= dd[mt][3];
                v[1] += v[0]; v[2] += v[1]; v[3] += v[2];
                acc[mt][nt] = v;
                t_[mt][nt] = v[3];
            }
        // xor-butterfly exclusive scan over 4 g-groups, serial over mt
        float Ofs[4][2];
#pragma unroll
        for (int nt = 0; nt < 2; ++nt) {
            float run = 0.0f;
#pragma unroll
            for (int mt = 0; mt < 4; ++mt) {
                float v    = t_[mt][nt];
                float p    = __shfl_xor(v, 16, 64);
                float excl = (g & 1) ? p : 0.0f;
                float pair = v + p;
                float q    = __shfl_xor(pair, 32, 64);
                excl += (g & 2) ? q : 0.0f;
                Ofs[mt][nt] = run + excl;
                run += pair + q;
            }
        }
#pragma unroll
        for (int mt = 0; mt < 4; ++mt)
#pragma unroll
            for (int r = 0; r < 4; ++r) {
                const int row = mt * 16 + g * 4 + r;
                const float dr = dd[mt][r];
#pragma unroll
                for (int nt = 0; nt < 2; ++nt) {
                    float val = (acc[mt][nt][r] + Ofs[mt][nt]) * dr + bias_c[nt];
                    ob[row * COUT + nt * 16] = fmaxf(val, 0.0f);
                }
            }
    };

    // ---- 5) barrier 1: LDS-only wait; g1's loads stay in flight ----
    LGKM_BARRIER();

    f32x4 acc0[4][2] = {};
    gemm((const unsigned char*)Xs4[0], acc0);

    // ---- 6) convert + ds_write g1 NOW (only g1's 8 loads outstanding).
    // buf1 is untouched by gemm-g0, and all waves passed barrier 1, so
    // writing it here is race-free and overlaps g0's epilogue. ----
#pragma unroll
    for (int i = 0; i < 4; ++i) {
        int ch  = tid + i * 512;
        int row = ch >> 5;
        int c8  = (ch & 31) << 3;
        f32x4 v0 = pg[2 * i], v1 = pg[2 * i + 1];
        bf16x8 h;
        h[0] = (__bf16)v0[0]; h[1] = (__bf16)v0[1];
        h[2] = (__bf16)v0[2]; h[3] = (__bf16)v0[3];
        h[4] = (__bf16)v1[0]; h[5] = (__bf16)v1[1];
        h[6] = (__bf16)v1[2]; h[7] = (__bf16)v1[3];
        int byte = (row << 9) + (c8 << 1);
        byte ^= (row & 7) << 4;
        *reinterpret_cast<uint4*>((unsigned char*)Xs4[1] + byte) =
            __builtin_bit_cast(uint4, h);
    }

    // ---- 7) g0 epilogue (stores fly; never drained by a barrier) ----
    epilogue(acc0, out + (size_t)xg * (NNODE * COUT) + colbase + c);

    // ---- 8) barrier 2: LDS-only wait (g0 stores keep draining) ----
    LGKM_BARRIER();

    f32x4 acc1[4][2] = {};
    gemm((const unsigned char*)Xs4[1], acc1);
    epilogue(acc1, out + (size_t)(xg + 1) * (NNODE * COUT) + colbase + c);
}

extern "C" void kernel_launch(void* const* d_in, const int* in_sizes, int n_in,
                              void* d_out, int out_size, void* d_ws, size_t ws_size,
                              hipStream_t stream) {
    const float* x = (const float*)d_in[0];
    const float* W = (const float*)d_in[1];
    const float* bsp = (const float*)d_in[2];
    float* out = (float*)d_out;

    hipLaunchKernelGGL(gcn_fused, dim3(BATCH / 2), dim3(512), 0, stream,
                       x, W, bsp, out);
}